// Round 2
// baseline (375.154 us; speedup 1.0000x reference)
//
#include <hip/hip_runtime.h>

// GCN, algebraically collapsed + CSR gather (no f32 feature atomics):
//   y[n]    = dinv[n] * x[n]                       (8 floats per node)
//   a[d]    = dinv[d] * ( sum_{s->d} y[s] + y[d] ) (gather over in-edge CSR)
//   h1[d]   = relu(a[d] @ W1 + b1)
//   c[d]    = dinv[d]*sdeg[d] + dinv[d]^2,  sdeg[s] = sum_{d: s->d} dinv[d]
//   v       = sum_d c[d] * h1[d]                   (layer2 + mean-pool collapse)
//   g       = (1/N) * v @ W2 + b2
//   out     = concat(g, relu(state@Wm+bm)) @ Wc + bc

__global__ void k_hist(const int* __restrict__ dst, unsigned* __restrict__ degi, int E) {
    int i = blockIdx.x * blockDim.x + threadIdx.x;
    if (i < E) atomicAdd(&degi[dst[i]], 1u);
}

// Per-1024-chunk degree sums.
__global__ void k_p1(const unsigned* __restrict__ degi, unsigned* __restrict__ bsum, int N) {
    __shared__ unsigned red[256];
    int t = threadIdx.x;
    int i0 = blockIdx.x * 1024 + t * 4;
    unsigned s = 0;
#pragma unroll
    for (int r = 0; r < 4; ++r) { int i = i0 + r; if (i < N) s += degi[i]; }
    red[t] = s;
    __syncthreads();
    for (int o = 128; o > 0; o >>= 1) {
        if (t < o) red[t] += red[t + o];
        __syncthreads();
    }
    if (t == 0) bsum[blockIdx.x] = red[0];
}

// Exclusive scan of block sums (nb <= 128), single block of 128 threads.
__global__ void k_p2(const unsigned* __restrict__ bsum, unsigned* __restrict__ bexcl, int nb) {
    __shared__ unsigned s[128];
    int t = threadIdx.x;
    unsigned v = (t < nb) ? bsum[t] : 0u;
    s[t] = v;
    __syncthreads();
    for (int o = 1; o < 128; o <<= 1) {
        unsigned add = (t >= o) ? s[t - o] : 0u;
        __syncthreads();
        s[t] += add;
        __syncthreads();
    }
    if (t < nb) bexcl[t] = s[t] - v;
}

// offs/cur = global exclusive scan; dinv = rsqrt(deg+1); y = dinv*x.
__global__ void k_p3(const unsigned* __restrict__ degi, const unsigned* __restrict__ bexcl,
                     const float* __restrict__ x,
                     unsigned* __restrict__ offs, unsigned* __restrict__ cur,
                     float* __restrict__ dinv, float* __restrict__ y, int N) {
    __shared__ unsigned s[256];
    int t = threadIdx.x;
    int i0 = blockIdx.x * 1024 + t * 4;
    unsigned d[4];
    unsigned tsum = 0;
#pragma unroll
    for (int r = 0; r < 4; ++r) {
        int i = i0 + r;
        d[r] = (i < N) ? degi[i] : 0u;
        tsum += d[r];
    }
    s[t] = tsum;
    __syncthreads();
    for (int o = 1; o < 256; o <<= 1) {
        unsigned add = (t >= o) ? s[t - o] : 0u;
        __syncthreads();
        s[t] += add;
        __syncthreads();
    }
    unsigned base = bexcl[blockIdx.x] + s[t] - tsum;
#pragma unroll
    for (int r = 0; r < 4; ++r) {
        int i = i0 + r;
        if (i < N) {
            offs[i] = base;
            cur[i]  = base;
            base += d[r];
            float di = rsqrtf((float)(d[r] + 1u));
            dinv[i] = di;
            float4 u0 = ((const float4*)(x + (size_t)i * 8))[0];
            float4 u1 = ((const float4*)(x + (size_t)i * 8))[1];
            u0.x *= di; u0.y *= di; u0.z *= di; u0.w *= di;
            u1.x *= di; u1.y *= di; u1.z *= di; u1.w *= di;
            ((float4*)(y + (size_t)i * 8))[0] = u0;
            ((float4*)(y + (size_t)i * 8))[1] = u1;
        }
    }
}

// Place each edge's source into the dst-CSR; accumulate sdeg[s] += dinv[d].
__global__ void k_binplace(const int* __restrict__ src, const int* __restrict__ dst,
                           const float* __restrict__ dinv,
                           unsigned* __restrict__ cur, int* __restrict__ srt,
                           float* __restrict__ sdeg, int E) {
    int e = blockIdx.x * blockDim.x + threadIdx.x;
    if (e >= E) return;
    int s = src[e], d = dst[e];
    unsigned p = atomicAdd(&cur[d], 1u);
    srt[p] = s;
    unsafeAtomicAdd(&sdeg[s], dinv[d]);
}

// One thread per node: gather y over in-edges, h1 = relu(a@W1+b1),
// acc[k] = c*h1[k]; butterfly reduce-scatter across the wave -> lane k holds
// the wave's sum of component k; LDS-reduce 4 waves -> vpart[block][64].
__launch_bounds__(256)
__global__ void k_fused(const float* __restrict__ y, const int* __restrict__ srt,
                        const unsigned* __restrict__ offs, const unsigned* __restrict__ cur,
                        const float* __restrict__ dinv, const float* __restrict__ sdeg,
                        const float* __restrict__ W1, const float* __restrict__ b1,
                        float* __restrict__ vpart, int N) {
    __shared__ float W1s[512];
    __shared__ float b1s[64];
    __shared__ float red[4][64];
    int t = threadIdx.x;
    for (int i = t; i < 512; i += 256) W1s[i] = W1[i];
    if (t < 64) b1s[t] = b1[t];
    __syncthreads();

    int n = blockIdx.x * 256 + t;
    float a[8] = {0.f, 0.f, 0.f, 0.f, 0.f, 0.f, 0.f, 0.f};
    float c = 0.f;
    if (n < N) {
        unsigned e0 = offs[n], e1 = cur[n];
        for (unsigned e = e0; e < e1; ++e) {
            int s = srt[e];
            float4 u0 = ((const float4*)(y + (size_t)s * 8))[0];
            float4 u1 = ((const float4*)(y + (size_t)s * 8))[1];
            a[0] += u0.x; a[1] += u0.y; a[2] += u0.z; a[3] += u0.w;
            a[4] += u1.x; a[5] += u1.y; a[6] += u1.z; a[7] += u1.w;
        }
        float4 s0 = ((const float4*)(y + (size_t)n * 8))[0];
        float4 s1 = ((const float4*)(y + (size_t)n * 8))[1];
        a[0] += s0.x; a[1] += s0.y; a[2] += s0.z; a[3] += s0.w;
        a[4] += s1.x; a[5] += s1.y; a[6] += s1.z; a[7] += s1.w;
        float di = dinv[n];
#pragma unroll
        for (int j = 0; j < 8; ++j) a[j] *= di;
        c = fmaf(di, sdeg[n], di * di);
    }

    float acc[64];
#pragma unroll
    for (int k = 0; k < 64; ++k) {
        float h = b1s[k];
#pragma unroll
        for (int j = 0; j < 8; ++j) h = fmaf(a[j], W1s[j * 64 + k], h);
        h = fmaxf(h, 0.f);
        acc[k] = c * h;
    }

    // Butterfly reduce-scatter: after 6 steps, acc[0] on lane l = sum over
    // the wave's 64 threads of their original acc[l].
    int lane = t & 63;
#pragma unroll
    for (int half = 32; half >= 1; half >>= 1) {
        bool upper = (lane & half) != 0;
#pragma unroll
        for (int i = 0; i < 32; ++i) {
            if (i >= half) break;
            float lo = acc[i];
            float hi = acc[i + half];
            float give = upper ? lo : hi;
            float keep = upper ? hi : lo;
            float recv = __shfl_xor(give, half);
            acc[i] = keep + recv;
        }
    }

    int wid = t >> 6;
    red[wid][lane] = acc[0];
    __syncthreads();
    if (t < 64)
        vpart[(size_t)blockIdx.x * 64 + t] =
            red[0][t] + red[1][t] + red[2][t] + red[3][t];
}

// Single block, 64 threads: reduce vpart, g = (1/N)*v@W2 + b2,
// s = relu(state@Wm+bm), out = [g,s]@Wc + bc.
__global__ void k_final(const float* __restrict__ vpart, int NB,
                        const float* __restrict__ W2, const float* __restrict__ b2,
                        const float* __restrict__ state, const float* __restrict__ Wm,
                        const float* __restrict__ bm, const float* __restrict__ Wc,
                        const float* __restrict__ bc, float* __restrict__ out,
                        float inv_n) {
    __shared__ float v[64];
    __shared__ float gs[128];
    int k = threadIdx.x;   // blockDim = 64

    float acc = 0.f;
    for (int b = 0; b < NB; ++b) acc += vpart[(size_t)b * 64 + k];
    v[k] = acc;
    __syncthreads();

    float g = 0.f;
    for (int j = 0; j < 64; ++j) g = fmaf(v[j], W2[j * 64 + k], g);
    g = fmaf(g, inv_n, b2[k]);

    float s = bm[k];
    for (int j = 0; j < 8; ++j) s = fmaf(state[j], Wm[j * 64 + k], s);
    s = fmaxf(s, 0.f);

    gs[k] = g;
    gs[64 + k] = s;
    __syncthreads();

    if (k < 2) {
        float o = bc[k];
        for (int j = 0; j < 128; ++j) o = fmaf(gs[j], Wc[j * 2 + k], o);
        out[k] = o;
    }
}

extern "C" void kernel_launch(void* const* d_in, const int* in_sizes, int n_in,
                              void* d_out, int out_size, void* d_ws, size_t ws_size,
                              hipStream_t stream) {
    const float* x     = (const float*)d_in[0];
    const float* state = (const float*)d_in[1];
    const float* W1    = (const float*)d_in[2];
    const float* b1    = (const float*)d_in[3];
    const float* W2    = (const float*)d_in[4];
    const float* b2    = (const float*)d_in[5];
    const float* Wm    = (const float*)d_in[6];
    const float* bm    = (const float*)d_in[7];
    const float* Wc    = (const float*)d_in[8];
    const float* bc    = (const float*)d_in[9];
    const int*   ei    = (const int*)d_in[10];

    const int N = in_sizes[0] / 8;
    const int E = in_sizes[10] / 2;
    const int* src = ei;
    const int* dst = ei + E;

    char* ws = (char*)d_ws;
    size_t off = 0;
    auto alloc = [&](size_t bytes) -> void* {
        void* p = ws + off;
        off += (bytes + 255) & ~(size_t)255;
        return p;
    };
    // Zeroed region first.
    unsigned* degi = (unsigned*)alloc((size_t)N * 4);
    float*    sdeg = (float*)   alloc((size_t)N * 4);
    size_t zero_bytes = off;
    // No-init region.
    unsigned* offs  = (unsigned*)alloc((size_t)N * 4);
    unsigned* cur   = (unsigned*)alloc((size_t)N * 4);
    float*    dinv  = (float*)   alloc((size_t)N * 4);
    unsigned* bsum  = (unsigned*)alloc(1024 * 4);
    unsigned* bexcl = (unsigned*)alloc(1024 * 4);
    float*    y     = (float*)   alloc((size_t)N * 8 * 4);
    int*      srt   = (int*)     alloc((size_t)E * 4);
    const int NBF = (N + 255) / 256;          // fused-kernel blocks (391)
    float*    vpart = (float*)   alloc((size_t)NBF * 64 * 4);
    (void)ws_size; (void)n_in; (void)out_size;

    hipMemsetAsync(d_ws, 0, zero_bytes, stream);

    const int NSB = (N + 1023) / 1024;        // scan blocks (98)

    k_hist<<<(E + 255) / 256, 256, 0, stream>>>(dst, degi, E);
    k_p1<<<NSB, 256, 0, stream>>>(degi, bsum, N);
    k_p2<<<1, 128, 0, stream>>>(bsum, bexcl, NSB);
    k_p3<<<NSB, 256, 0, stream>>>(degi, bexcl, x, offs, cur, dinv, y, N);
    k_binplace<<<(E + 255) / 256, 256, 0, stream>>>(src, dst, dinv, cur, srt, sdeg, E);
    k_fused<<<NBF, 256, 0, stream>>>(y, srt, offs, cur, dinv, sdeg, W1, b1, vpart, N);
    k_final<<<1, 64, 0, stream>>>(vpart, NBF, W2, b2, state, Wm, bm, Wc, bc,
                                  (float*)d_out, 1.0f / (float)N);
}

// Round 3
// 294.312 us; speedup vs baseline: 1.2747x; 1.2747x over previous
//
#include <hip/hip_runtime.h>

// GCN, algebraically collapsed + two-sided 256-node bucket partition.
// All scatter is LDS-local; global writes are dense; no global fp32 atomics.
//   y[n]  = dinv[n]*x[n]
//   a[d]  = dinv[d]*(sum_{s->d} y[s] + y[d])
//   h1[d] = relu(a[d] @ W1 + b1)
//   c[d]  = dinv[d]*sdeg[d] + dinv[d]^2,  sdeg[s] = sum_{d: s->d} dinv[d]
//   v     = sum_d c[d]*h1[d];  g = (1/N)*v@W2 + b2
//   out   = concat(g, relu(state@Wm+bm)) @ Wc + bc

#define NPB   256      // nodes per bucket (power of 2)
#define CAP   4096     // edge capacity per bucket (Poisson mean ~3197, +14 sigma)
#define MAXB  512      // max buckets (N <= 131072)

// Partition edges into dst-keyed and src-keyed buckets in one pass.
// Payload u32: low 17 bits = other-endpoint node id, bits [24:17] = own low-8.
__launch_bounds__(256)
__global__ void k_part(const int* __restrict__ src, const int* __restrict__ dst,
                       int E, int nbuck,
                       unsigned* __restrict__ curD, unsigned* __restrict__ curS,
                       unsigned* __restrict__ bufD, unsigned* __restrict__ bufS) {
    __shared__ unsigned lcD[MAXB], lcS[MAXB], gbD[MAXB], gbS[MAXB];
    int t = threadIdx.x;
    for (int i = t; i < nbuck; i += 256) { lcD[i] = 0; lcS[i] = 0; }
    __syncthreads();
    int base = blockIdx.x * (256 * 16);
    unsigned wD[16], wS[16], rr[16], bb[16];
#pragma unroll
    for (int k = 0; k < 16; ++k) {
        int e = base + k * 256 + t;
        if (e < E) {
            unsigned s = (unsigned)src[e], d = (unsigned)dst[e];
            unsigned bD = d >> 8, bS = s >> 8;
            wD[k] = s | ((d & 255u) << 17);
            wS[k] = d | ((s & 255u) << 17);
            unsigned rD = atomicAdd(&lcD[bD], 1u);
            unsigned rS = atomicAdd(&lcS[bS], 1u);
            rr[k] = rD | (rS << 16);
            bb[k] = bD | (bS << 16);
        } else {
            wD[k] = 0xffffffffu;
        }
    }
    __syncthreads();
    for (int i = t; i < nbuck; i += 256) {
        unsigned c = lcD[i];
        gbD[i] = c ? atomicAdd(&curD[i], c) : 0u;
        c = lcS[i];
        gbS[i] = c ? atomicAdd(&curS[i], c) : 0u;
    }
    __syncthreads();
#pragma unroll
    for (int k = 0; k < 16; ++k) {
        if (wD[k] == 0xffffffffu) continue;
        unsigned bD = bb[k] & 0xffffu, bS = bb[k] >> 16;
        bufD[(size_t)bD * CAP + gbD[bD] + (rr[k] & 0xffffu)] = wD[k];
        bufS[(size_t)bS * CAP + gbS[bS] + (rr[k] >> 16)]     = wS[k];
    }
}

// Per dst-bucket: in-degree via LDS atomics -> dinv, y = dinv*x (coalesced).
__launch_bounds__(256)
__global__ void k_prep(const unsigned* __restrict__ bufD, const unsigned* __restrict__ cntD,
                       const float* __restrict__ x, int N,
                       float* __restrict__ dinv, float* __restrict__ y) {
    __shared__ unsigned degl[NPB];
    int t = threadIdx.x, b = blockIdx.x;
    degl[t] = 0u;
    __syncthreads();
    unsigned cnt = cntD[b];
    const unsigned* eb = bufD + (size_t)b * CAP;
    for (unsigned i = t; i < cnt; i += 256) atomicAdd(&degl[eb[i] >> 17], 1u);
    __syncthreads();
    int n = b * NPB + t;
    if (n < N) {
        float di = rsqrtf((float)(degl[t] + 1u));
        dinv[n] = di;
        float4 u0 = ((const float4*)(x + (size_t)n * 8))[0];
        float4 u1 = ((const float4*)(x + (size_t)n * 8))[1];
        u0.x *= di; u0.y *= di; u0.z *= di; u0.w *= di;
        u1.x *= di; u1.y *= di; u1.z *= di; u1.w *= di;
        ((float4*)(y + (size_t)n * 8))[0] = u0;
        ((float4*)(y + (size_t)n * 8))[1] = u1;
    }
}

// Per src-bucket: sdeg[s] = sum dinv[dst] via LDS float atomics.
__launch_bounds__(256)
__global__ void k_sdeg(const unsigned* __restrict__ bufS, const unsigned* __restrict__ cntS,
                       const float* __restrict__ dinv, int N,
                       float* __restrict__ sdeg) {
    __shared__ float sl[NPB];
    int t = threadIdx.x, b = blockIdx.x;
    sl[t] = 0.f;
    __syncthreads();
    unsigned cnt = cntS[b];
    const unsigned* eb = bufS + (size_t)b * CAP;
    for (unsigned i = t; i < cnt; i += 256) {
        unsigned w = eb[i];
        atomicAdd(&sl[w >> 17], dinv[w & 0x1ffffu]);
    }
    __syncthreads();
    int n = b * NPB + t;
    if (n < N) sdeg[n] = sl[t];
}

// Per dst-bucket: accumulate y[src] into padded LDS acc, then fused node math
// (h1 = relu(a@W1+b1), weighted by c) + butterfly reduce-scatter -> vpart.
__launch_bounds__(256)
__global__ void k_acc(const unsigned* __restrict__ bufD, const unsigned* __restrict__ cntD,
                      const float* __restrict__ y, const float* __restrict__ dinv,
                      const float* __restrict__ sdeg,
                      const float* __restrict__ W1, const float* __restrict__ b1,
                      float* __restrict__ vpart, int N) {
    __shared__ float acc[NPB][9];   // +1 pad: spread dl*9 across all 32 banks
    __shared__ float W1s[512];
    __shared__ float b1s[64];
    __shared__ float red[4][64];
    int t = threadIdx.x, b = blockIdx.x;
    for (int i = t; i < 512; i += 256) W1s[i] = W1[i];
    if (t < 64) b1s[t] = b1[t];
#pragma unroll
    for (int j = 0; j < 9; ++j) acc[t][j] = 0.f;
    __syncthreads();

    unsigned cnt = cntD[b];
    const unsigned* eb = bufD + (size_t)b * CAP;
    for (unsigned i = t; i < cnt; i += 256) {
        unsigned w = eb[i];
        unsigned s = w & 0x1ffffu;
        unsigned dl = w >> 17;
        float4 u0 = ((const float4*)(y + (size_t)s * 8))[0];
        float4 u1 = ((const float4*)(y + (size_t)s * 8))[1];
        atomicAdd(&acc[dl][0], u0.x);
        atomicAdd(&acc[dl][1], u0.y);
        atomicAdd(&acc[dl][2], u0.z);
        atomicAdd(&acc[dl][3], u0.w);
        atomicAdd(&acc[dl][4], u1.x);
        atomicAdd(&acc[dl][5], u1.y);
        atomicAdd(&acc[dl][6], u1.z);
        atomicAdd(&acc[dl][7], u1.w);
    }
    __syncthreads();

    int n = b * NPB + t;
    float a[8] = {0.f, 0.f, 0.f, 0.f, 0.f, 0.f, 0.f, 0.f};
    float c = 0.f;
    if (n < N) {
        float di = dinv[n];
        float4 s0 = ((const float4*)(y + (size_t)n * 8))[0];
        float4 s1 = ((const float4*)(y + (size_t)n * 8))[1];
        a[0] = di * (acc[t][0] + s0.x);
        a[1] = di * (acc[t][1] + s0.y);
        a[2] = di * (acc[t][2] + s0.z);
        a[3] = di * (acc[t][3] + s0.w);
        a[4] = di * (acc[t][4] + s1.x);
        a[5] = di * (acc[t][5] + s1.y);
        a[6] = di * (acc[t][6] + s1.z);
        a[7] = di * (acc[t][7] + s1.w);
        c = fmaf(di, sdeg[n], di * di);
    }

    float vv[64];
#pragma unroll
    for (int k = 0; k < 64; ++k) {
        float h = b1s[k];
#pragma unroll
        for (int j = 0; j < 8; ++j) h = fmaf(a[j], W1s[j * 64 + k], h);
        vv[k] = c * fmaxf(h, 0.f);
    }

    // Butterfly reduce-scatter (validated round 2): lane l ends with wave-sum
    // of component l in vv[0].
    int lane = t & 63;
#pragma unroll
    for (int half = 32; half >= 1; half >>= 1) {
        bool upper = (lane & half) != 0;
#pragma unroll
        for (int i = 0; i < 32; ++i) {
            if (i >= half) break;
            float lo = vv[i];
            float hi = vv[i + half];
            float give = upper ? lo : hi;
            float keep = upper ? hi : lo;
            float recv = __shfl_xor(give, half);
            vv[i] = keep + recv;
        }
    }

    int wid = t >> 6;
    red[wid][lane] = vv[0];
    __syncthreads();
    if (t < 64)
        vpart[(size_t)b * 64 + t] = red[0][t] + red[1][t] + red[2][t] + red[3][t];
}

// Single block, 64 threads: reduce vpart, g = (1/N)*v@W2+b2,
// s = relu(state@Wm+bm), out = [g,s]@Wc+bc.
__global__ void k_final(const float* __restrict__ vpart, int NB,
                        const float* __restrict__ W2, const float* __restrict__ b2,
                        const float* __restrict__ state, const float* __restrict__ Wm,
                        const float* __restrict__ bm, const float* __restrict__ Wc,
                        const float* __restrict__ bc, float* __restrict__ out,
                        float inv_n) {
    __shared__ float v[64];
    __shared__ float gs[128];
    int k = threadIdx.x;   // blockDim = 64

    float acc = 0.f;
    for (int b = 0; b < NB; ++b) acc += vpart[(size_t)b * 64 + k];
    v[k] = acc;
    __syncthreads();

    float g = 0.f;
    for (int j = 0; j < 64; ++j) g = fmaf(v[j], W2[j * 64 + k], g);
    g = fmaf(g, inv_n, b2[k]);

    float s = bm[k];
    for (int j = 0; j < 8; ++j) s = fmaf(state[j], Wm[j * 64 + k], s);
    s = fmaxf(s, 0.f);

    gs[k] = g;
    gs[64 + k] = s;
    __syncthreads();

    if (k < 2) {
        float o = bc[k];
        for (int j = 0; j < 128; ++j) o = fmaf(gs[j], Wc[j * 2 + k], o);
        out[k] = o;
    }
}

extern "C" void kernel_launch(void* const* d_in, const int* in_sizes, int n_in,
                              void* d_out, int out_size, void* d_ws, size_t ws_size,
                              hipStream_t stream) {
    const float* x     = (const float*)d_in[0];
    const float* state = (const float*)d_in[1];
    const float* W1    = (const float*)d_in[2];
    const float* b1    = (const float*)d_in[3];
    const float* W2    = (const float*)d_in[4];
    const float* b2    = (const float*)d_in[5];
    const float* Wm    = (const float*)d_in[6];
    const float* bm    = (const float*)d_in[7];
    const float* Wc    = (const float*)d_in[8];
    const float* bc    = (const float*)d_in[9];
    const int*   ei    = (const int*)d_in[10];

    const int N = in_sizes[0] / 8;
    const int E = in_sizes[10] / 2;
    const int* src = ei;
    const int* dst = ei + E;
    const int nbuck = (N + NPB - 1) / NPB;   // 391 for N=100000

    char* ws = (char*)d_ws;
    size_t off = 0;
    auto alloc = [&](size_t bytes) -> void* {
        void* p = ws + off;
        off += (bytes + 255) & ~(size_t)255;
        return p;
    };
    // Zeroed region: the two cursor arrays only (4 KB).
    unsigned* curD = (unsigned*)alloc((size_t)MAXB * 4);
    unsigned* curS = (unsigned*)alloc((size_t)MAXB * 4);
    size_t zero_bytes = off;
    // No-init region.
    unsigned* bufD  = (unsigned*)alloc((size_t)nbuck * CAP * 4);
    unsigned* bufS  = (unsigned*)alloc((size_t)nbuck * CAP * 4);
    float*    dinv  = (float*)   alloc((size_t)N * 4);
    float*    y     = (float*)   alloc((size_t)N * 8 * 4);
    float*    sdeg  = (float*)   alloc((size_t)N * 4);
    float*    vpart = (float*)   alloc((size_t)nbuck * 64 * 4);
    (void)ws_size; (void)n_in; (void)out_size;

    hipMemsetAsync(d_ws, 0, zero_bytes, stream);

    k_part<<<(E + 4095) / 4096, 256, 0, stream>>>(src, dst, E, nbuck,
                                                  curD, curS, bufD, bufS);
    k_prep<<<nbuck, 256, 0, stream>>>(bufD, curD, x, N, dinv, y);
    k_sdeg<<<nbuck, 256, 0, stream>>>(bufS, curS, dinv, N, sdeg);
    k_acc <<<nbuck, 256, 0, stream>>>(bufD, curD, y, dinv, sdeg, W1, b1, vpart, N);
    k_final<<<1, 64, 0, stream>>>(vpart, nbuck, W2, b2, state, Wm, bm, Wc, bc,
                                  (float*)d_out, 1.0f / (float)N);
}

// Round 4
// 199.468 us; speedup vs baseline: 1.8808x; 1.4755x over previous
//
#include <hip/hip_runtime.h>

// GCN, algebraically collapsed + two-sided 256-node bucket partition.
// All scatter is LDS-local; per-block results fold into vsum[64] via 25K
// global f32 atomics (no serial reduction tail).
//   y[n]  = dinv[n]*x[n]
//   a[d]  = dinv[d]*(sum_{s->d} y[s] + y[d])
//   h1[d] = relu(a[d] @ W1 + b1)
//   c[d]  = dinv[d]*sdeg[d] + dinv[d]^2,  sdeg[s] = sum_{d: s->d} dinv[d]
//   v     = sum_d c[d]*h1[d];  g = (1/N)*v@W2 + b2
//   out   = concat(g, relu(state@Wm+bm)) @ Wc + bc

#define NPB   256      // nodes per bucket (power of 2)
#define CAP   4096     // edge capacity per bucket (Poisson mean ~3197, +15.9 sigma)
#define MAXB  512      // max buckets (N <= 131072)

// Partition edges into dst-keyed and src-keyed buckets in one pass.
// Payload u32: low 17 bits = other-endpoint node id, bits [24:17] = own low-8.
__launch_bounds__(256)
__global__ void k_part(const int* __restrict__ src, const int* __restrict__ dst,
                       int E, int nbuck,
                       unsigned* __restrict__ curD, unsigned* __restrict__ curS,
                       unsigned* __restrict__ bufD, unsigned* __restrict__ bufS) {
    __shared__ unsigned lcD[MAXB], lcS[MAXB], gbD[MAXB], gbS[MAXB];
    int t = threadIdx.x;
    for (int i = t; i < nbuck; i += 256) { lcD[i] = 0; lcS[i] = 0; }
    __syncthreads();
    int base = blockIdx.x * (256 * 16);
    unsigned wD[16], wS[16], rr[16], bb[16];
#pragma unroll
    for (int k = 0; k < 16; ++k) {
        int e = base + k * 256 + t;
        if (e < E) {
            unsigned s = (unsigned)src[e], d = (unsigned)dst[e];
            unsigned bD = d >> 8, bS = s >> 8;
            wD[k] = s | ((d & 255u) << 17);
            wS[k] = d | ((s & 255u) << 17);
            unsigned rD = atomicAdd(&lcD[bD], 1u);
            unsigned rS = atomicAdd(&lcS[bS], 1u);
            rr[k] = rD | (rS << 16);
            bb[k] = bD | (bS << 16);
        } else {
            wD[k] = 0xffffffffu;
        }
    }
    __syncthreads();
    for (int i = t; i < nbuck; i += 256) {
        unsigned c = lcD[i];
        gbD[i] = c ? atomicAdd(&curD[i], c) : 0u;
        c = lcS[i];
        gbS[i] = c ? atomicAdd(&curS[i], c) : 0u;
    }
    __syncthreads();
#pragma unroll
    for (int k = 0; k < 16; ++k) {
        if (wD[k] == 0xffffffffu) continue;
        unsigned bD = bb[k] & 0xffffu, bS = bb[k] >> 16;
        bufD[(size_t)bD * CAP + gbD[bD] + (rr[k] & 0xffffu)] = wD[k];
        bufS[(size_t)bS * CAP + gbS[bS] + (rr[k] >> 16)]     = wS[k];
    }
}

// Per dst-bucket: in-degree via LDS atomics -> dinv, y = dinv*x (coalesced).
__launch_bounds__(256)
__global__ void k_prep(const unsigned* __restrict__ bufD, const unsigned* __restrict__ cntD,
                       const float* __restrict__ x, int N,
                       float* __restrict__ dinv, float* __restrict__ y) {
    __shared__ unsigned degl[NPB];
    int t = threadIdx.x, b = blockIdx.x;
    degl[t] = 0u;
    __syncthreads();
    unsigned cnt = cntD[b];
    const unsigned* eb = bufD + (size_t)b * CAP;
    for (unsigned i = t; i < cnt; i += 256) atomicAdd(&degl[eb[i] >> 17], 1u);
    __syncthreads();
    int n = b * NPB + t;
    if (n < N) {
        float di = rsqrtf((float)(degl[t] + 1u));
        dinv[n] = di;
        float4 u0 = ((const float4*)(x + (size_t)n * 8))[0];
        float4 u1 = ((const float4*)(x + (size_t)n * 8))[1];
        u0.x *= di; u0.y *= di; u0.z *= di; u0.w *= di;
        u1.x *= di; u1.y *= di; u1.z *= di; u1.w *= di;
        ((float4*)(y + (size_t)n * 8))[0] = u0;
        ((float4*)(y + (size_t)n * 8))[1] = u1;
    }
}

// Per bucket b (same index for src- and dst-side):
//   sl[t]  = sdeg for node b*256+t   (LDS atomics over bufS)
//   acc[t] = sum of y[src] in-edges  (LDS atomics over bufD)
// then fused node math + butterfly reduce-scatter; block result folds into
// global vsum[64] via unsafeAtomicAdd.
__launch_bounds__(256)
__global__ void k_sacc(const unsigned* __restrict__ bufD, const unsigned* __restrict__ cntD,
                       const unsigned* __restrict__ bufS, const unsigned* __restrict__ cntS,
                       const float* __restrict__ y, const float* __restrict__ dinv,
                       const float* __restrict__ W1, const float* __restrict__ b1,
                       float* __restrict__ vsum, int N) {
    __shared__ float acc[NPB][9];   // +1 pad: spread dl*9 across all 32 banks
    __shared__ float sl[NPB];
    __shared__ float W1s[512];
    __shared__ float b1s[64];
    __shared__ float red[4][64];
    int t = threadIdx.x, b = blockIdx.x;
    for (int i = t; i < 512; i += 256) W1s[i] = W1[i];
    if (t < 64) b1s[t] = b1[t];
#pragma unroll
    for (int j = 0; j < 9; ++j) acc[t][j] = 0.f;
    sl[t] = 0.f;
    __syncthreads();

    // sdeg side (src-bucket b)
    {
        unsigned cnt = cntS[b];
        const unsigned* eb = bufS + (size_t)b * CAP;
        for (unsigned i = t; i < cnt; i += 256) {
            unsigned w = eb[i];
            atomicAdd(&sl[w >> 17], dinv[w & 0x1ffffu]);
        }
    }
    // feature-accumulate side (dst-bucket b)
    {
        unsigned cnt = cntD[b];
        const unsigned* eb = bufD + (size_t)b * CAP;
        for (unsigned i = t; i < cnt; i += 256) {
            unsigned w = eb[i];
            unsigned s = w & 0x1ffffu;
            unsigned dl = w >> 17;
            float4 u0 = ((const float4*)(y + (size_t)s * 8))[0];
            float4 u1 = ((const float4*)(y + (size_t)s * 8))[1];
            atomicAdd(&acc[dl][0], u0.x);
            atomicAdd(&acc[dl][1], u0.y);
            atomicAdd(&acc[dl][2], u0.z);
            atomicAdd(&acc[dl][3], u0.w);
            atomicAdd(&acc[dl][4], u1.x);
            atomicAdd(&acc[dl][5], u1.y);
            atomicAdd(&acc[dl][6], u1.z);
            atomicAdd(&acc[dl][7], u1.w);
        }
    }
    __syncthreads();

    int n = b * NPB + t;
    float a[8] = {0.f, 0.f, 0.f, 0.f, 0.f, 0.f, 0.f, 0.f};
    float c = 0.f;
    if (n < N) {
        float di = dinv[n];
        float4 s0 = ((const float4*)(y + (size_t)n * 8))[0];
        float4 s1 = ((const float4*)(y + (size_t)n * 8))[1];
        a[0] = di * (acc[t][0] + s0.x);
        a[1] = di * (acc[t][1] + s0.y);
        a[2] = di * (acc[t][2] + s0.z);
        a[3] = di * (acc[t][3] + s0.w);
        a[4] = di * (acc[t][4] + s1.x);
        a[5] = di * (acc[t][5] + s1.y);
        a[6] = di * (acc[t][6] + s1.z);
        a[7] = di * (acc[t][7] + s1.w);
        c = fmaf(di, sl[t], di * di);
    }

    float vv[64];
#pragma unroll
    for (int k = 0; k < 64; ++k) {
        float h = b1s[k];
#pragma unroll
        for (int j = 0; j < 8; ++j) h = fmaf(a[j], W1s[j * 64 + k], h);
        vv[k] = c * fmaxf(h, 0.f);
    }

    // Butterfly reduce-scatter (validated R2/R3): lane l ends with wave-sum of
    // component l in vv[0].
    int lane = t & 63;
#pragma unroll
    for (int half = 32; half >= 1; half >>= 1) {
        bool upper = (lane & half) != 0;
#pragma unroll
        for (int i = 0; i < 32; ++i) {
            if (i >= half) break;
            float lo = vv[i];
            float hi = vv[i + half];
            float give = upper ? lo : hi;
            float keep = upper ? hi : lo;
            float recv = __shfl_xor(give, half);
            vv[i] = keep + recv;
        }
    }

    int wid = t >> 6;
    red[wid][lane] = vv[0];
    __syncthreads();
    if (t < 64)
        unsafeAtomicAdd(&vsum[t], red[0][t] + red[1][t] + red[2][t] + red[3][t]);
}

// Single block, 64 threads: g = (1/N)*vsum@W2+b2, s = relu(state@Wm+bm),
// out = [g,s]@Wc+bc.  Tiny: reads 64 floats + ~17 KB weights.
__global__ void k_final(const float* __restrict__ vsum,
                        const float* __restrict__ W2, const float* __restrict__ b2,
                        const float* __restrict__ state, const float* __restrict__ Wm,
                        const float* __restrict__ bm, const float* __restrict__ Wc,
                        const float* __restrict__ bc, float* __restrict__ out,
                        float inv_n) {
    __shared__ float v[64];
    __shared__ float gs[128];
    int k = threadIdx.x;   // blockDim = 64

    v[k] = vsum[k];
    __syncthreads();

    float g = 0.f;
    for (int j = 0; j < 64; ++j) g = fmaf(v[j], W2[j * 64 + k], g);
    g = fmaf(g, inv_n, b2[k]);

    float s = bm[k];
    for (int j = 0; j < 8; ++j) s = fmaf(state[j], Wm[j * 64 + k], s);
    s = fmaxf(s, 0.f);

    gs[k] = g;
    gs[64 + k] = s;
    __syncthreads();

    if (k < 2) {
        float o = bc[k];
        for (int j = 0; j < 128; ++j) o = fmaf(gs[j], Wc[j * 2 + k], o);
        out[k] = o;
    }
}

extern "C" void kernel_launch(void* const* d_in, const int* in_sizes, int n_in,
                              void* d_out, int out_size, void* d_ws, size_t ws_size,
                              hipStream_t stream) {
    const float* x     = (const float*)d_in[0];
    const float* state = (const float*)d_in[1];
    const float* W1    = (const float*)d_in[2];
    const float* b1    = (const float*)d_in[3];
    const float* W2    = (const float*)d_in[4];
    const float* b2    = (const float*)d_in[5];
    const float* Wm    = (const float*)d_in[6];
    const float* bm    = (const float*)d_in[7];
    const float* Wc    = (const float*)d_in[8];
    const float* bc    = (const float*)d_in[9];
    const int*   ei    = (const int*)d_in[10];

    const int N = in_sizes[0] / 8;
    const int E = in_sizes[10] / 2;
    const int* src = ei;
    const int* dst = ei + E;
    const int nbuck = (N + NPB - 1) / NPB;   // 391 for N=100000

    char* ws = (char*)d_ws;
    size_t off = 0;
    auto alloc = [&](size_t bytes) -> void* {
        void* p = ws + off;
        off += (bytes + 255) & ~(size_t)255;
        return p;
    };
    // Zeroed region: cursors + vsum (~4.3 KB).
    unsigned* curD = (unsigned*)alloc((size_t)MAXB * 4);
    unsigned* curS = (unsigned*)alloc((size_t)MAXB * 4);
    float*    vsum = (float*)   alloc(64 * 4);
    size_t zero_bytes = off;
    // No-init region.
    unsigned* bufD  = (unsigned*)alloc((size_t)nbuck * CAP * 4);
    unsigned* bufS  = (unsigned*)alloc((size_t)nbuck * CAP * 4);
    float*    dinv  = (float*)   alloc((size_t)N * 4);
    float*    y     = (float*)   alloc((size_t)N * 8 * 4);
    (void)ws_size; (void)n_in; (void)out_size;

    hipMemsetAsync(d_ws, 0, zero_bytes, stream);

    k_part<<<(E + 4095) / 4096, 256, 0, stream>>>(src, dst, E, nbuck,
                                                  curD, curS, bufD, bufS);
    k_prep<<<nbuck, 256, 0, stream>>>(bufD, curD, x, N, dinv, y);
    k_sacc<<<nbuck, 256, 0, stream>>>(bufD, curD, bufS, curS, y, dinv,
                                      W1, b1, vsum, N);
    k_final<<<1, 64, 0, stream>>>(vsum, W2, b2, state, Wm, bm, Wc, bc,
                                  (float*)d_out, 1.0f / (float)N);
}

// Round 5
// 196.004 us; speedup vs baseline: 1.9140x; 1.0177x over previous
//
#include <hip/hip_runtime.h>

// GCN, algebraically collapsed + two-sided 256-node bucket partition.
//   y[n]  = dinv[n]*x[n]
//   a[d]  = dinv[d]*(sum_{s->d} y[s] + y[d])
//   h1[d] = relu(a[d] @ W1 + b1)
//   c[d]  = dinv[d]*sdeg[d] + dinv[d]^2,  sdeg[s] = sum_{d: s->d} dinv[d]
//   v     = sum_d c[d]*h1[d];  g = (1/N)*v@W2 + b2
//   out   = concat(g, relu(state@Wm+bm)) @ Wc + bc
// R5 changes: k_part is an LDS-staged radix scatter (contiguous run writes,
// no 4B random scatter); k_prep/k_sacc use 1024-thread blocks (occupancy was
// 14% with 256-thread blocks at 391 blocks -> latency-bound gathers).

#define NPB   256      // nodes per bucket (power of 2)
#define CAP   4096     // edge capacity per bucket (Poisson mean ~3197, +15.9 sigma)
#define MAXB  512      // max buckets (N <= 131072)
#define PCH   4096     // edges per partition block
#define PTH   512      // partition block threads
#define PK    (PCH/PTH) // 8 edges per thread

// Block-level radix scatter: per 4096-edge chunk, rank edges into buckets via
// LDS atomics, exclusive-scan counts, stage bucket-ordered in LDS, then write
// contiguous runs to global (consecutive lanes -> consecutive addresses).
// Payload u32: low 17 bits = other-endpoint node id, bits [24:17] = own low-8.
__launch_bounds__(PTH)
__global__ void k_part(const int* __restrict__ src, const int* __restrict__ dst,
                       int E, int nbuck,
                       unsigned* __restrict__ curD, unsigned* __restrict__ curS,
                       unsigned* __restrict__ bufD, unsigned* __restrict__ bufS) {
    __shared__ unsigned       stage[PCH];   // 16 KB
    __shared__ unsigned short bkt[PCH];     //  8 KB
    __shared__ unsigned lc[MAXB], lofs[MAXB], gb[MAXB], sc[MAXB]; // 8 KB
    int t = threadIdx.x;
    int base = blockIdx.x * PCH;
    int cnt = min(PCH, E - base);

    unsigned ss[PK], dd[PK];
#pragma unroll
    for (int k = 0; k < PK; ++k) {
        int e = base + k * PTH + t;
        if (e < E) { ss[k] = (unsigned)src[e]; dd[k] = (unsigned)dst[e]; }
        else ss[k] = 0xffffffffu;
    }

    for (int side = 0; side < 2; ++side) {
        lc[t] = 0;             // PTH == MAXB
        __syncthreads();

        unsigned br[PK];
#pragma unroll
        for (int k = 0; k < PK; ++k) {
            if (ss[k] == 0xffffffffu) { br[k] = 0xffffffffu; continue; }
            unsigned key = side ? ss[k] : dd[k];
            unsigned b = key >> 8;
            unsigned r = atomicAdd(&lc[b], 1u);
            br[k] = (b << 16) | r;
        }
        __syncthreads();

        // exclusive scan of lc[0..MAXB) with PTH==MAXB threads
        unsigned v = lc[t];
        sc[t] = v;
        __syncthreads();
        for (int o = 1; o < MAXB; o <<= 1) {
            unsigned add = (t >= o) ? sc[t - o] : 0u;
            __syncthreads();
            sc[t] += add;
            __syncthreads();
        }
        lofs[t] = sc[t] - v;
        gb[t] = v ? atomicAdd(side ? &curS[t] : &curD[t], v) : 0u;
        __syncthreads();

        // stage bucket-ordered
#pragma unroll
        for (int k = 0; k < PK; ++k) {
            if (br[k] == 0xffffffffu) continue;
            unsigned b = br[k] >> 16, r = br[k] & 0xffffu;
            unsigned pos = lofs[b] + r;
            stage[pos] = side ? (dd[k] | ((ss[k] & 255u) << 17))
                              : (ss[k] | ((dd[k] & 255u) << 17));
            bkt[pos] = (unsigned short)b;
        }
        __syncthreads();

        // contiguous-run writeout
        unsigned* obuf = side ? bufS : bufD;
        for (int i = t; i < cnt; i += PTH) {
            unsigned b = bkt[i];
            obuf[(size_t)b * CAP + gb[b] + ((unsigned)i - lofs[b])] = stage[i];
        }
        __syncthreads();
    }
}

// Per dst-bucket: in-degree via LDS atomics -> dinv, y = dinv*x (coalesced).
__launch_bounds__(1024)
__global__ void k_prep(const unsigned* __restrict__ bufD, const unsigned* __restrict__ cntD,
                       const float* __restrict__ x, int N,
                       float* __restrict__ dinv, float* __restrict__ y) {
    __shared__ unsigned degl[NPB];
    int t = threadIdx.x, b = blockIdx.x;
    if (t < NPB) degl[t] = 0u;
    __syncthreads();
    unsigned cnt = cntD[b];
    const unsigned* eb = bufD + (size_t)b * CAP;
    for (unsigned i = t; i < cnt; i += 1024) atomicAdd(&degl[eb[i] >> 17], 1u);
    __syncthreads();
    if (t < NPB) {
        int n = b * NPB + t;
        if (n < N) {
            float di = rsqrtf((float)(degl[t] + 1u));
            dinv[n] = di;
            float4 u0 = ((const float4*)(x + (size_t)n * 8))[0];
            float4 u1 = ((const float4*)(x + (size_t)n * 8))[1];
            u0.x *= di; u0.y *= di; u0.z *= di; u0.w *= di;
            u1.x *= di; u1.y *= di; u1.z *= di; u1.w *= di;
            ((float4*)(y + (size_t)n * 8))[0] = u0;
            ((float4*)(y + (size_t)n * 8))[1] = u1;
        }
    }
}

// Per bucket b: sl[t] = sdeg (LDS atomics over bufS); acc[t] = sum of in-edge
// y[src] (LDS atomics over bufD); then fused node math + butterfly
// reduce-scatter; block result folds into global vsum[64].
__launch_bounds__(1024, 4)
__global__ void k_sacc(const unsigned* __restrict__ bufD, const unsigned* __restrict__ cntD,
                       const unsigned* __restrict__ bufS, const unsigned* __restrict__ cntS,
                       const float* __restrict__ y, const float* __restrict__ dinv,
                       const float* __restrict__ W1, const float* __restrict__ b1,
                       float* __restrict__ vsum, int N) {
    __shared__ float acc[NPB][9];   // +1 pad: spread dl*9 across all 32 banks
    __shared__ float sl[NPB];
    __shared__ float W1s[512];
    __shared__ float b1s[64];
    __shared__ float red[4][64];
    int t = threadIdx.x, b = blockIdx.x;
    if (t < 512) W1s[t] = W1[t];
    else if (t < 576) b1s[t - 512] = b1[t - 512];
    if (t < NPB) {
#pragma unroll
        for (int j = 0; j < 9; ++j) acc[t][j] = 0.f;
        sl[t] = 0.f;
    }
    __syncthreads();

    // sdeg side (src-bucket b)
    {
        unsigned cnt = cntS[b];
        const unsigned* eb = bufS + (size_t)b * CAP;
        for (unsigned i = t; i < cnt; i += 1024) {
            unsigned w = eb[i];
            atomicAdd(&sl[w >> 17], dinv[w & 0x1ffffu]);
        }
    }
    // feature-accumulate side (dst-bucket b)
    {
        unsigned cnt = cntD[b];
        const unsigned* eb = bufD + (size_t)b * CAP;
        for (unsigned i = t; i < cnt; i += 1024) {
            unsigned w = eb[i];
            unsigned s = w & 0x1ffffu;
            unsigned dl = w >> 17;
            float4 u0 = ((const float4*)(y + (size_t)s * 8))[0];
            float4 u1 = ((const float4*)(y + (size_t)s * 8))[1];
            atomicAdd(&acc[dl][0], u0.x);
            atomicAdd(&acc[dl][1], u0.y);
            atomicAdd(&acc[dl][2], u0.z);
            atomicAdd(&acc[dl][3], u0.w);
            atomicAdd(&acc[dl][4], u1.x);
            atomicAdd(&acc[dl][5], u1.y);
            atomicAdd(&acc[dl][6], u1.z);
            atomicAdd(&acc[dl][7], u1.w);
        }
    }
    __syncthreads();

    if (t < NPB) {
        int n = b * NPB + t;
        float a[8] = {0.f, 0.f, 0.f, 0.f, 0.f, 0.f, 0.f, 0.f};
        float c = 0.f;
        if (n < N) {
            float di = dinv[n];
            float4 s0 = ((const float4*)(y + (size_t)n * 8))[0];
            float4 s1 = ((const float4*)(y + (size_t)n * 8))[1];
            a[0] = di * (acc[t][0] + s0.x);
            a[1] = di * (acc[t][1] + s0.y);
            a[2] = di * (acc[t][2] + s0.z);
            a[3] = di * (acc[t][3] + s0.w);
            a[4] = di * (acc[t][4] + s1.x);
            a[5] = di * (acc[t][5] + s1.y);
            a[6] = di * (acc[t][6] + s1.z);
            a[7] = di * (acc[t][7] + s1.w);
            c = fmaf(di, sl[t], di * di);
        }

        float vv[64];
#pragma unroll
        for (int k = 0; k < 64; ++k) {
            float h = b1s[k];
#pragma unroll
            for (int j = 0; j < 8; ++j) h = fmaf(a[j], W1s[j * 64 + k], h);
            vv[k] = c * fmaxf(h, 0.f);
        }

        // Butterfly reduce-scatter (validated R2-R4): lane l ends with
        // wave-sum of component l in vv[0].
        int lane = t & 63;
#pragma unroll
        for (int half = 32; half >= 1; half >>= 1) {
            bool upper = (lane & half) != 0;
#pragma unroll
            for (int i = 0; i < 32; ++i) {
                if (i >= half) break;
                float lo = vv[i];
                float hi = vv[i + half];
                float give = upper ? lo : hi;
                float keep = upper ? hi : lo;
                float recv = __shfl_xor(give, half);
                vv[i] = keep + recv;
            }
        }
        red[t >> 6][lane] = vv[0];
    }
    __syncthreads();
    if (t < 64)
        unsafeAtomicAdd(&vsum[t], red[0][t] + red[1][t] + red[2][t] + red[3][t]);
}

// Single block, 64 threads: g = (1/N)*vsum@W2+b2, s = relu(state@Wm+bm),
// out = [g,s]@Wc+bc.
__global__ void k_final(const float* __restrict__ vsum,
                        const float* __restrict__ W2, const float* __restrict__ b2,
                        const float* __restrict__ state, const float* __restrict__ Wm,
                        const float* __restrict__ bm, const float* __restrict__ Wc,
                        const float* __restrict__ bc, float* __restrict__ out,
                        float inv_n) {
    __shared__ float v[64];
    __shared__ float gs[128];
    int k = threadIdx.x;   // blockDim = 64

    v[k] = vsum[k];
    __syncthreads();

    float g = 0.f;
    for (int j = 0; j < 64; ++j) g = fmaf(v[j], W2[j * 64 + k], g);
    g = fmaf(g, inv_n, b2[k]);

    float s = bm[k];
    for (int j = 0; j < 8; ++j) s = fmaf(state[j], Wm[j * 64 + k], s);
    s = fmaxf(s, 0.f);

    gs[k] = g;
    gs[64 + k] = s;
    __syncthreads();

    if (k < 2) {
        float o = bc[k];
        for (int j = 0; j < 128; ++j) o = fmaf(gs[j], Wc[j * 2 + k], o);
        out[k] = o;
    }
}

extern "C" void kernel_launch(void* const* d_in, const int* in_sizes, int n_in,
                              void* d_out, int out_size, void* d_ws, size_t ws_size,
                              hipStream_t stream) {
    const float* x     = (const float*)d_in[0];
    const float* state = (const float*)d_in[1];
    const float* W1    = (const float*)d_in[2];
    const float* b1    = (const float*)d_in[3];
    const float* W2    = (const float*)d_in[4];
    const float* b2    = (const float*)d_in[5];
    const float* Wm    = (const float*)d_in[6];
    const float* bm    = (const float*)d_in[7];
    const float* Wc    = (const float*)d_in[8];
    const float* bc    = (const float*)d_in[9];
    const int*   ei    = (const int*)d_in[10];

    const int N = in_sizes[0] / 8;
    const int E = in_sizes[10] / 2;
    const int* src = ei;
    const int* dst = ei + E;
    const int nbuck = (N + NPB - 1) / NPB;   // 391 for N=100000

    char* ws = (char*)d_ws;
    size_t off = 0;
    auto alloc = [&](size_t bytes) -> void* {
        void* p = ws + off;
        off += (bytes + 255) & ~(size_t)255;
        return p;
    };
    // Zeroed region: cursors + vsum (~4.4 KB).
    unsigned* curD = (unsigned*)alloc((size_t)MAXB * 4);
    unsigned* curS = (unsigned*)alloc((size_t)MAXB * 4);
    float*    vsum = (float*)   alloc(64 * 4);
    size_t zero_bytes = off;
    // No-init region.
    unsigned* bufD  = (unsigned*)alloc((size_t)nbuck * CAP * 4);
    unsigned* bufS  = (unsigned*)alloc((size_t)nbuck * CAP * 4);
    float*    dinv  = (float*)   alloc((size_t)N * 4);
    float*    y     = (float*)   alloc((size_t)N * 8 * 4);
    (void)ws_size; (void)n_in; (void)out_size;

    hipMemsetAsync(d_ws, 0, zero_bytes, stream);

    k_part<<<(E + PCH - 1) / PCH, PTH, 0, stream>>>(src, dst, E, nbuck,
                                                    curD, curS, bufD, bufS);
    k_prep<<<nbuck, 1024, 0, stream>>>(bufD, curD, x, N, dinv, y);
    k_sacc<<<nbuck, 1024, 0, stream>>>(bufD, curD, bufS, curS, y, dinv,
                                       W1, b1, vsum, N);
    k_final<<<1, 64, 0, stream>>>(vsum, W2, b2, state, Wm, bm, Wc, bc,
                                  (float*)d_out, 1.0f / (float)N);
}